// Round 5
// baseline (15819.553 us; speedup 1.0000x reference)
//
#include <hip/hip_runtime.h>
#include <cmath>

#define L_     10
#define R_     64
#define G_     128
#define S_     256
#define MEL_   80
#define NCLS_  256
#define HOP_   64
#define END_   256
#define FRAMES_ 8
#define T_     512

typedef unsigned long long u64;

// ---- workspace layout (float offsets; all mailbox offsets 8B-aligned) ----
#define COND8_OFF   0                                // 8*1280
#define HIST_OFF    10240                            // layers 1..8: [(j-1)][512][64]
#define MBX64_OFF   (HIST_OFF + 8*T_*R_)             // u64 x mailboxes [4][64] (0..2 used)
#define CTR64_OFF   (MBX64_OFF + 4*R_*2)             // u64 contribs [10][256] (0..8 used)
#define HID64_OFF   (CTR64_OFF + 10*S_*2)            // u64 T3->T4 [256]
#define FLAG_OFF    (HID64_OFF + S_*2)               // flags, 16 ints apart

#define FID_PREV   11
#define FID_CLAIM  12

#define NROLE 5
#define SPIN_CAP (1 << 16)

// ====== tagged 64-bit mailbox protocol (XCD-0 pinned), r14 transport ======
// r13(RMW)=8.58ms, r14(this)=8.85, r15(rel/acq)=24.7, r17(sc0-local)=11.1:
// hop cost ~1.7us is transport-invariant (device-coherence-point latency).
// This round attacks HOP COUNT (7->5) instead; transport is the r14-proven
// one: slot=(tag<<32)|payload in one 8B word (no ordering hazard possible),
// push = relaxed agent store, poll = relaxed agent load with every-16th
// returning-atomic fallback. Poison (0xAA..) reads as negative tag.
__device__ __forceinline__ void push_tag(u64* p, float v, int tag) {
  u64 pk = ((u64)(unsigned)tag << 32) | (unsigned)__float_as_int(v);
  __hip_atomic_store(p, pk, __ATOMIC_RELAXED, __HIP_MEMORY_SCOPE_AGENT);
}
__device__ __forceinline__ u64 atomic_slot(u64* p) {
  u64 r;
  asm volatile("global_atomic_add_x2 %0, %1, %2, off sc0\n\ts_waitcnt vmcnt(0)"
               : "=&v"(r) : "v"(p), "v"(0ULL) : "memory");
  return r;
}
__device__ __forceinline__ float poll_tag(u64* p, int want) {
  u64 r; int n = 0;
  for (;;) {
    r = ((n & 15) == 15)
            ? atomic_slot(p)
            : __hip_atomic_load(p, __ATOMIC_RELAXED, __HIP_MEMORY_SCOPE_AGENT);
    if ((int)(r >> 32) >= want) break;
    if (++n > SPIN_CAP) break;
  }
  return __int_as_float((int)(unsigned)(r & 0xffffffffULL));
}
__device__ __forceinline__ float2 poll_tag2(u64* p0, u64* p1, int want) {
  u64 r0, r1; int n = 0;
  for (;;) {
    if ((n & 15) == 15) {
      r0 = atomic_slot(p0);
      r1 = atomic_slot(p1);
    } else {
      r0 = __hip_atomic_load(p0, __ATOMIC_RELAXED, __HIP_MEMORY_SCOPE_AGENT);
      r1 = __hip_atomic_load(p1, __ATOMIC_RELAXED, __HIP_MEMORY_SCOPE_AGENT);
    }
    if ((int)(r0 >> 32) >= want && (int)(r1 >> 32) >= want) break;
    if (++n > SPIN_CAP) break;
  }
  return make_float2(__int_as_float((int)(unsigned)(r0 & 0xffffffffULL)),
                     __int_as_float((int)(unsigned)(r1 & 0xffffffffULL)));
}
__device__ __forceinline__ int flag_atomic(int* p) {
  int v;
  asm volatile("global_atomic_add %0, %1, %2, off sc0\n\ts_waitcnt vmcnt(0)"
               : "=&v"(v) : "v"(p), "v"(0) : "memory");
  return v;
}
__device__ __forceinline__ void push_flag(int* p, int v) {
  __hip_atomic_store(p, v, __ATOMIC_RELAXED, __HIP_MEMORY_SCOPE_AGENT);
}
__device__ __forceinline__ int wait_prev_wave(int* p, int want, int lane) {
  int v = 0, n = 0;
  do {
    if (lane == 0)
      v = ((n & 15) == 15)
              ? flag_atomic(p)
              : __hip_atomic_load(p, __ATOMIC_RELAXED, __HIP_MEMORY_SCOPE_AGENT);
    v = __shfl(v, 0, 64);
    if ((v >> 16) >= want) break;
  } while (++n <= SPIN_CAP);
  return v & 0xffff;
}

// ---- single-chain dot macros: EXACT r8/r13 arithmetic (absmax 0.0 proven).
#define DOTREG(N4, W, V4, ACC) do { \
  _Pragma("unroll") \
  for (int k_ = 0; k_ < (N4); ++k_) { float4 a_ = (V4)[k_]; \
    ACC = fmaf((W)[4*k_+0], a_.x, ACC); ACC = fmaf((W)[4*k_+1], a_.y, ACC); \
    ACC = fmaf((W)[4*k_+2], a_.z, ACC); ACC = fmaf((W)[4*k_+3], a_.w, ACC); } \
} while (0)

#define DOTREG_RELU(N4, W, V4, ACC) do { \
  _Pragma("unroll") \
  for (int k_ = 0; k_ < (N4); ++k_) { float4 a_ = (V4)[k_]; \
    a_.x = fmaxf(a_.x, 0.f); a_.y = fmaxf(a_.y, 0.f); \
    a_.z = fmaxf(a_.z, 0.f); a_.w = fmaxf(a_.w, 0.f); \
    ACC = fmaf((W)[4*k_+0], a_.x, ACC); ACC = fmaf((W)[4*k_+1], a_.y, ACC); \
    ACC = fmaf((W)[4*k_+2], a_.z, ACC); ACC = fmaf((W)[4*k_+3], a_.w, ACC); } \
} while (0)

// fused gate+z (r9-proven, bit-identical h): threads<128, gr=tid>>1, gh=tid&1
#define GATE(WXW, WXF, SRC, PDW, PDF, DST) do { \
  const float4* xs4_ = (const float4*)((SRC) + gh * 32); \
  float vw_ = 0.f, vf_ = 0.f; \
  DOTREG(8, WXW, xs4_, vw_); \
  DOTREG(8, WXF, xs4_, vf_); \
  vw_ += __shfl_down(vw_, 1, 2); \
  vf_ += __shfl_down(vf_, 1, 2); \
  if (gh == 0) { \
    float hw_ = vw_ + (PDW), hf_ = vf_ + (PDF); \
    (DST)[gr] = tanhf(hw_) * (1.f / (1.f + expf(-hf_))); \
  } \
} while (0)

// pd precompute for layer JL at t+1 (r9-proven streamed-WVp form)
#define PDPRE(JL, DIL, HISTP, USEX, CND, PDW, PDF) do { \
  const float4* pw_ = (const float4*)(WVp + ((size_t)((JL) * G_ + gr)) * R_ + gh * 32); \
  const float4* pf_ = (const float4*)(WVp + ((size_t)((JL) * G_ + gr + 64)) * R_ + gh * 32); \
  _Pragma("unroll") \
  for (int i = 0; i < 8; ++i) { ((float4*)wpw)[i] = pw_[i]; ((float4*)wpf)[i] = pf_[i]; } \
  if (USEX) { \
    _Pragma("unroll") \
    for (int i = 0; i < 8; ++i) ((float4*)pa)[i] = ((const float4*)(x_s + gh * 32))[i]; \
  } else { \
    const int tp_ = tn - (DIL); \
    if (tp_ >= 0) { \
      const float4* hp_ = (const float4*)((HISTP) + (size_t)tp_ * R_ + gh * 32); \
      _Pragma("unroll") \
      for (int i = 0; i < 8; ++i) ((float4*)pa)[i] = hp_[i]; \
    } else { \
      _Pragma("unroll") \
      for (int i = 0; i < 32; ++i) pa[i] = 0.f; \
    } \
  } \
  { float vw_ = 0.f, vf_ = 0.f; const float4* pa4_ = (const float4*)pa; \
    DOTREG(8, wpw, pa4_, vw_); \
    DOTREG(8, wpf, pa4_, vf_); \
    vw_ += __shfl_down(vw_, 1, 2); \
    vf_ += __shfl_down(vf_, 1, 2); \
    if (gh == 0) { PDW = vw_ + (CND)[f1 * G_ + gr]; PDF = vf_ + (CND)[f1 * G_ + gr + 64]; } } \
} while (0)

__global__ void cond_prep_kernel(const float* __restrict__ condW,
                                 const float* __restrict__ y,
                                 float* __restrict__ cond8) {
  int idx = blockIdx.x * blockDim.x + threadIdx.x;
  if (idx >= FRAMES_ * L_ * G_) return;
  int f = idx / (L_ * G_);
  int row = idx - f * (L_ * G_);
  float acc = 0.f;
  for (int m = 0; m < MEL_; ++m)
    acc = fmaf(condW[row * MEL_ + m], y[m * FRAMES_ + f], acc);
  cond8[f * (L_ * G_) + row] = acc;
}

__global__ __launch_bounds__(256, 1) void wavenet_pipe(
    const float* __restrict__ samples,
    const int*   __restrict__ c_ptr,
    const float* __restrict__ emb,
    const float* __restrict__ WVp,
    const float* __restrict__ WVx,
    const float* __restrict__ Wo,
    const float* __restrict__ Wob,
    const float* __restrict__ Wol,
    const float* __restrict__ Wobl,
    const float* __restrict__ e1w,
    const float* __restrict__ e1b,
    const float* __restrict__ e2w,
    const float* __restrict__ e2b,
    float* __restrict__ ws,
    int*   __restrict__ out) {

  const int tid = threadIdx.x;

  float* cond8   = ws + COND8_OFF;
  float* hist    = ws + HIST_OFF;
  u64*   mbx     = (u64*)(ws + MBX64_OFF);
  u64*   contrib = (u64*)(ws + CTR64_OFF);
  u64*   mbhid   = (u64*)(ws + HID64_OFF);
  int*   flags   = (int*)(ws + FLAG_OFF);
  int*   fprev   = flags + FID_PREV * 16;

  __shared__ __align__(16) float x_s[R_];
  __shared__ __align__(16) float xb_s[R_];
  __shared__ __align__(16) float xc_s[R_];
  __shared__ __align__(16) float z_s[R_];
  __shared__ __align__(16) float cond_s0[FRAMES_ * G_];
  __shared__ __align__(16) float cond_s1[FRAMES_ * G_];  // T4 reuses as logits
  __shared__ __align__(16) float cond_s2[FRAMES_ * G_];
  __shared__ __align__(16) float biasC_s[10 * S_];       // T3 only
  __shared__ __align__(16) float vec_s[S_];
  __shared__ __align__(16) float emb_s[NCLS_ * R_];      // T0 only: 64KB LDS
  __shared__ float wred[4], wsum[4];
  __shared__ int wcand[4];
  __shared__ int role_s;

  // ---- XCD-pinned role claiming (r7-proven) ----
  {
    unsigned xcc;
    asm volatile("s_getreg_b32 %0, hwreg(HW_REG_XCC_ID)" : "=s"(xcc));
    if (tid == 0) {
      int r = -1;
      if (xcc == 0) {
        int c0 = atomicAdd(flags + FID_CLAIM * 16, 1);
        if (c0 < NROLE) r = c0;
      }
      role_s = r;
    }
    __syncthreads();
  }
  const int bid = role_s;
  if (bid < 0) return;

  if (bid < 3) {
    // ============ T_q: layer triple j0=3q, j1=3q+1, j2=3q+2 ============
    const int q = bid;
    const int j0 = 3 * q, j1 = 3 * q + 1, j2 = 3 * q + 2;
    const int dil0 = 1 << j0, dil1 = 1 << j1, dil2 = 1 << j2;
    const int gr = tid >> 1, gh = tid & 1;

    float wx0w[32], wx0f[32], wx1w[32], wx1f[32], wx2w[32], wx2f[32];
    float wo0[64], wo1[64], wo2[64], wex[64];
    float b0, b1, b2;
    if (tid < 128) {
      const float4* p;
      p = (const float4*)(WVx + ((size_t)(j0 * G_ + gr)) * R_ + gh * 32);
      #pragma unroll
      for (int i = 0; i < 8; ++i) ((float4*)wx0w)[i] = p[i];
      p = (const float4*)(WVx + ((size_t)(j0 * G_ + gr + 64)) * R_ + gh * 32);
      #pragma unroll
      for (int i = 0; i < 8; ++i) ((float4*)wx0f)[i] = p[i];
      p = (const float4*)(WVx + ((size_t)(j1 * G_ + gr)) * R_ + gh * 32);
      #pragma unroll
      for (int i = 0; i < 8; ++i) ((float4*)wx1w)[i] = p[i];
      p = (const float4*)(WVx + ((size_t)(j1 * G_ + gr + 64)) * R_ + gh * 32);
      #pragma unroll
      for (int i = 0; i < 8; ++i) ((float4*)wx1f)[i] = p[i];
      p = (const float4*)(WVx + ((size_t)(j2 * G_ + gr)) * R_ + gh * 32);
      #pragma unroll
      for (int i = 0; i < 8; ++i) ((float4*)wx2w)[i] = p[i];
      p = (const float4*)(WVx + ((size_t)(j2 * G_ + gr + 64)) * R_ + gh * 32);
      #pragma unroll
      for (int i = 0; i < 8; ++i) ((float4*)wx2f)[i] = p[i];
    }
    {
      const float* qq;
      qq = Wo + ((size_t)(j0 * (R_ + S_) + tid)) * R_;
      #pragma unroll
      for (int i = 0; i < 64; ++i) wo0[i] = qq[i];
      b0 = Wob[j0 * (R_ + S_) + tid];
      qq = Wo + ((size_t)(j1 * (R_ + S_) + tid)) * R_;
      #pragma unroll
      for (int i = 0; i < 64; ++i) wo1[i] = qq[i];
      b1 = Wob[j1 * (R_ + S_) + tid];
      qq = Wo + ((size_t)(j2 * (R_ + S_) + tid)) * R_;
      #pragma unroll
      for (int i = 0; i < 64; ++i) wo2[i] = qq[i];
      b2 = Wob[j2 * (R_ + S_) + tid];
      // wex: skip rows 256..319 of layer (tid<64 -> j0, <128 -> j1, <192 -> j2)
      if (tid < 64) {
        qq = Wo + ((size_t)(j0 * (R_ + S_) + 256 + tid)) * R_;
        #pragma unroll
        for (int i = 0; i < 64; ++i) wex[i] = qq[i];
      } else if (tid < 128) {
        qq = Wo + ((size_t)(j1 * (R_ + S_) + 256 + (tid - 64))) * R_;
        #pragma unroll
        for (int i = 0; i < 64; ++i) wex[i] = qq[i];
      } else if (tid < 192) {
        qq = Wo + ((size_t)(j2 * (R_ + S_) + 256 + (tid - 128))) * R_;
        #pragma unroll
        for (int i = 0; i < 64; ++i) wex[i] = qq[i];
      }
    }
    for (int i = tid; i < FRAMES_ * G_; i += 256) {
      cond_s0[i] = cond8[(i >> 7) * (L_ * G_) + j0 * G_ + (i & 127)];
      cond_s1[i] = cond8[(i >> 7) * (L_ * G_) + j1 * G_ + (i & 127)];
      cond_s2[i] = cond8[(i >> 7) * (L_ * G_) + j2 * G_ + (i & 127)];
    }
    if (q == 0) {
      for (int i = tid; i < NCLS_ * R_ / 4; i += 256)
        ((float4*)emb_s)[i] = ((const float4*)emb)[i];
    }
    __syncthreads();
    float pd0w = 0.f, pd0f = 0.f, pd1w = 0.f, pd1f = 0.f, pd2w = 0.f, pd2f = 0.f;
    if (tid < 128 && gh == 0) {
      pd0w = cond_s0[gr]; pd0f = cond_s0[gr + 64];
      pd1w = cond_s1[gr]; pd1f = cond_s1[gr + 64];
      pd2w = cond_s2[gr]; pd2f = cond_s2[gr + 64];
    }

    float* h0 = (j0 >= 1) ? (hist + (size_t)(j0 - 1) * T_ * R_) : nullptr;
    float* h1 = hist + (size_t)(j1 - 1) * T_ * R_;
    float* h2 = hist + (size_t)(j2 - 1) * T_ * R_;
    u64* mbx_in  = mbx + (size_t)(q - 1) * R_;   // q>=1
    u64* mbx_out = mbx + (size_t)q * R_;
    u64* c0p = contrib + (size_t)j0 * S_;
    u64* c1p = contrib + (size_t)j1 * S_;
    u64* c2p = contrib + (size_t)j2 * S_;

    for (int t = 0; t < T_; ++t) {
      // A: acquire x (wave 0)
      if (tid < 64) {
        if (q == 0) {
          int prev = 127;
          if (t > 0) prev = wait_prev_wave(fprev, t, tid);
          if (tid < 16)
            ((float4*)x_s)[tid] = ((const float4*)(emb_s + (size_t)prev * R_))[tid];
        } else {
          x_s[tid] = poll_tag(mbx_in + tid, t + 1);
        }
      }
      __syncthreads();  // (1) x ready

      // B: gate l0 ; hist_j0 <- x
      if (tid < 128) GATE(wx0w, wx0f, x_s, pd0w, pd0f, z_s);
      if (q > 0 && tid >= 240)
        ((float4*)(h0 + (size_t)t * R_))[tid - 240] = ((const float4*)x_s)[tid - 240];
      __syncthreads();  // (2) z0 ready

      // C: resid l0 + contrib_0 publishes (r13-exact rows/values)
      {
        const float4* z4 = (const float4*)z_s;
        if (tid < 64) {
          float v0 = 0.f, v1 = 0.f;
          DOTREG(16, wo0, z4, v0);
          DOTREG(16, wex, z4, v1);
          xb_s[tid] = x_s[tid] + v0 + b0;
          push_tag(c0p + 192 + tid, v1, t + 1);
        } else {
          float v0 = 0.f;
          DOTREG(16, wo0, z4, v0);
          push_tag(c0p + (tid - 64), v0, t + 1);
        }
      }
      __syncthreads();  // (3) xb ready

      // D: gate l1 ; hist_j1 <- xb
      if (tid < 128) GATE(wx1w, wx1f, xb_s, pd1w, pd1f, z_s);
      if (tid >= 224 && tid < 240)
        ((float4*)(h1 + (size_t)t * R_))[tid - 224] = ((const float4*)xb_s)[tid - 224];
      __syncthreads();  // (4) z1 ready

      // E: resid l1 + contrib_1 publishes
      {
        const float4* z4 = (const float4*)z_s;
        if (tid < 64) {
          float v0 = 0.f;
          DOTREG(16, wo1, z4, v0);
          xc_s[tid] = xb_s[tid] + v0 + b1;
        } else if (tid < 128) {
          float v0 = 0.f, v1 = 0.f;
          DOTREG(16, wo1, z4, v0);
          DOTREG(16, wex, z4, v1);
          push_tag(c1p + (tid - 64), v0, t + 1);
          push_tag(c1p + 192 + (tid - 64), v1, t + 1);
        } else {
          float v0 = 0.f;
          DOTREG(16, wo1, z4, v0);
          push_tag(c1p + (tid - 64), v0, t + 1);
        }
      }
      __syncthreads();  // (5) xc ready

      // F: gate l2 ; hist_j2 <- xc
      if (tid < 128) GATE(wx2w, wx2f, xc_s, pd2w, pd2f, z_s);
      if (tid >= 240)
        ((float4*)(h2 + (size_t)t * R_))[tid - 240] = ((const float4*)xc_s)[tid - 240];
      __syncthreads();  // (6) z2 ready

      // G: resid l2 -> mbx_out (critical edge FIRST) + contrib_2 publishes
      {
        const float4* z4 = (const float4*)z_s;
        if (tid < 64) {
          float v0 = 0.f;
          DOTREG(16, wo2, z4, v0);
          push_tag(mbx_out + tid, xc_s[tid] + v0 + b2, t + 1);
        } else if (tid < 128) {
          float v0 = 0.f;
          DOTREG(16, wo2, z4, v0);
          push_tag(c2p + (tid - 64), v0, t + 1);
        } else if (tid < 192) {
          float v0 = 0.f, v1 = 0.f;
          DOTREG(16, wo2, z4, v0);
          DOTREG(16, wex, z4, v1);
          push_tag(c2p + (tid - 64), v0, t + 1);
          push_tag(c2p + 192 + (tid - 128), v1, t + 1);
        } else {
          float v0 = 0.f;
          DOTREG(16, wo2, z4, v0);
          push_tag(c2p + (tid - 64), v0, t + 1);
        }
      }

      // H: pd precompute for t+1 (off critical path: downstream chain >> H)
      const int tn = t + 1;
      if (tn < T_ && tid < 128) {
        const int f1 = tn >> 6;
        float wpw[32], wpf[32], pa[32];
        if (q == 0) {
          PDPRE(j0, dil0, h0, true, cond_s0, pd0w, pd0f);   // past = x(t) = x_s
        } else {
          PDPRE(j0, dil0, h0, false, cond_s0, pd0w, pd0f);
        }
        PDPRE(j1, dil1, h1, false, cond_s1, pd1w, pd1f);
        PDPRE(j2, dil2, h2, false, cond_s2, pd2w, pd2f);
      }
      __syncthreads();  // (7) LDS buffers reusable at t+1
    }

  } else if (bid == 3) {
    // ============ T3: layer 9 + ordered skip fold + E1 ============
    const int gr = tid >> 1, gh = tid & 1;
    const int o_loc = tid >> 1, halfc = tid & 1;

    float wx9w[32], wx9f[32], wol9[64];
    float w0[128], w1[128];
    if (tid < 128) {
      const float4* p;
      p = (const float4*)(WVx + ((size_t)(9 * G_ + gr)) * R_ + gh * 32);
      #pragma unroll
      for (int i = 0; i < 8; ++i) ((float4*)wx9w)[i] = p[i];
      p = (const float4*)(WVx + ((size_t)(9 * G_ + gr + 64)) * R_ + gh * 32);
      #pragma unroll
      for (int i = 0; i < 8; ++i) ((float4*)wx9f)[i] = p[i];
    }
    {
      const float* qq = Wol + (size_t)tid * R_;
      #pragma unroll
      for (int i = 0; i < 64; ++i) wol9[i] = qq[i];
      const float* p = e1w + ((size_t)o_loc) * S_ + halfc * 128;
      #pragma unroll
      for (int i = 0; i < 128; ++i) w0[i] = p[i];
      p = e1w + ((size_t)(128 + o_loc)) * S_ + halfc * 128;
      #pragma unroll
      for (int i = 0; i < 128; ++i) w1[i] = p[i];
    }
    const float bias0 = e1b[o_loc], bias1 = e1b[128 + o_loc];
    for (int i = tid; i < 10 * S_; i += 256) {
      int j = i >> 8, s = i & 255;
      biasC_s[i] = (j < 9) ? Wob[j * (R_ + S_) + 64 + s] : Wobl[s];
    }
    for (int i = tid; i < FRAMES_ * G_; i += 256)
      cond_s0[i] = cond8[(i >> 7) * (L_ * G_) + 9 * G_ + (i & 127)];
    __syncthreads();

    u64* mbx_in = mbx + (size_t)2 * R_;

    for (int t = 0; t < T_; ++t) {
      // A: acquire x8 (wave 0)
      if (tid < 64) x_s[tid] = poll_tag(mbx_in + tid, t + 1);
      __syncthreads();

      // B: gate l9 (past always 0: dil=512; pd = cond only, same value/order)
      if (tid < 128) {
        const int f = t >> 6;
        GATE(wx9w, wx9f, x_s, cond_s0[f * G_ + gr], cond_s0[f * G_ + gr + 64], z_s);
      }
      __syncthreads();

      // C: v9 local (layer-9 contrib never leaves the block: one hop deleted)
      //    + ordered fold j=0..9 (r13-exact order: +v_j then +b_j)
      {
        const float4* z4 = (const float4*)z_s;
        float v9 = 0.f;
        DOTREG(16, wol9, z4, v9);
        float sacc = 0.f;
        for (int kk = 0; kk < 4; ++kk) {
          float2 v = poll_tag2(contrib + (size_t)(2 * kk) * S_ + tid,
                               contrib + (size_t)(2 * kk + 1) * S_ + tid, t + 1);
          sacc = (sacc + v.x) + biasC_s[(2 * kk) * S_ + tid];
          sacc = (sacc + v.y) + biasC_s[(2 * kk + 1) * S_ + tid];
        }
        float v8 = poll_tag(contrib + (size_t)8 * S_ + tid, t + 1);
        sacc = (sacc + v8) + biasC_s[8 * S_ + tid];
        sacc = (sacc + v9) + biasC_s[9 * S_ + tid];
        vec_s[tid] = sacc;
      }
      __syncthreads();

      // D: E1 (r8-exact) -> mbhid
      {
        const float4* s4 = (const float4*)(vec_s + halfc * 128);
        float v0 = 0.f, v1 = 0.f;
        DOTREG_RELU(32, w0, s4, v0);
        v0 += __shfl_down(v0, 1, 2);
        DOTREG_RELU(32, w1, s4, v1);
        v1 += __shfl_down(v1, 1, 2);
        if (halfc == 0) {
          push_tag(mbhid + o_loc,       fmaxf(v0 + bias0, 0.f), t + 1);
          push_tag(mbhid + 128 + o_loc, fmaxf(v1 + bias1, 0.f), t + 1);
        }
      }
      __syncthreads();  // vec_s / z_s / x_s reuse guard
    }

  } else {
    // ============ T4: E2 + sampling (r8-exact) ============
    const int o_loc = tid >> 1, halfc = tid & 1;
    const float cf = (float)c_ptr[0];
    float w0[128], w1[128];
    {
      const float* p = e2w + ((size_t)o_loc) * END_ + halfc * 128;
      #pragma unroll
      for (int i = 0; i < 128; ++i) w0[i] = p[i];
      p = e2w + ((size_t)(128 + o_loc)) * END_ + halfc * 128;
      #pragma unroll
      for (int i = 0; i < 128; ++i) w1[i] = p[i];
    }
    const float bias0 = e2b[o_loc], bias1 = e2b[128 + o_loc];
    float* logits_s = cond_s1;  // reuse (unused by T4)
    const int lane = tid & 63, wv = tid >> 6;

    for (int t = 0; t < T_; ++t) {
      vec_s[tid] = poll_tag(mbhid + tid, t + 1);
      __syncthreads();
      const float4* h4 = (const float4*)(vec_s + halfc * 128);
      float v0 = 0.f, v1 = 0.f;
      DOTREG(32, w0, h4, v0);
      v0 += __shfl_down(v0, 1, 2);
      DOTREG(32, w1, h4, v1);
      v1 += __shfl_down(v1, 1, 2);
      if (halfc == 0) {
        logits_s[o_loc]       = (v0 + bias0) * cf;
        logits_s[128 + o_loc] = (v1 + bias1) * cf;
      }
      __syncthreads();

      // ---- softmax-CDF sampling over 256 logits (r8 verbatim) ----
      float lg = logits_s[tid];
      float m = lg;
      #pragma unroll
      for (int off = 32; off >= 1; off >>= 1) m = fmaxf(m, __shfl_xor(m, off, 64));
      if (lane == 0) wred[wv] = m;
      __syncthreads();
      m = fmaxf(fmaxf(wred[0], wred[1]), fmaxf(wred[2], wred[3]));
      float e = expf(lg - m);
      float cs = e;
      #pragma unroll
      for (int off = 1; off < 64; off <<= 1) {
        float o_ = __shfl_up(cs, off, 64);
        if (lane >= off) cs += o_;
      }
      if (lane == 63) wsum[wv] = cs;
      __syncthreads();
      float total = wsum[0] + wsum[1] + wsum[2] + wsum[3];
      float offv = 0.f;
      for (int w2 = 0; w2 < wv; ++w2) offv += wsum[w2];
      float thresh = samples[t] * total;
      bool flagb = (offv + cs) > thresh;
      unsigned long long mk = __ballot(flagb);
      if (lane == 0) wcand[wv] = mk ? (wv * 64 + __ffsll(mk) - 1) : 100000;
      __syncthreads();
      if (tid == 0) {
        int nw = min(min(wcand[0], wcand[1]), min(wcand[2], wcand[3]));
        if (nw >= 100000) nw = 0;  // argmax of all-False -> 0
        out[t] = nw;
        push_flag(fprev, ((t + 1) << 16) | nw);
      }
      __syncthreads();  // protect wred/wsum/logits_s before next step
    }
  }
}

extern "C" void kernel_launch(void* const* d_in, const int* in_sizes, int n_in,
                              void* d_out, int out_size, void* d_ws, size_t ws_size,
                              hipStream_t stream) {
  const float* y       = (const float*)d_in[0];
  const float* samples = (const float*)d_in[1];
  const int*   c       = (const int*)d_in[2];
  const float* emb     = (const float*)d_in[3];
  const float* condW   = (const float*)d_in[4];
  const float* WVp     = (const float*)d_in[5];
  const float* WVx     = (const float*)d_in[6];
  const float* Wo      = (const float*)d_in[7];
  const float* Wob     = (const float*)d_in[8];
  const float* Wol     = (const float*)d_in[9];
  const float* Wobl    = (const float*)d_in[10];
  const float* e1w     = (const float*)d_in[11];
  const float* e1b     = (const float*)d_in[12];
  const float* e2w     = (const float*)d_in[13];
  const float* e2b     = (const float*)d_in[14];

  float* ws  = (float*)d_ws;
  int*   out = (int*)d_out;

  // Only flags need zeroing; mailbox tags rely on the 0xAA poison reading as
  // negative (never >= any t+1). Harness re-poisons ws before every launch.
  hipMemsetAsync((char*)d_ws + (size_t)FLAG_OFF * sizeof(float), 0,
                 16 * 16 * sizeof(int), stream);

  cond_prep_kernel<<<(FRAMES_ * L_ * G_ + 255) / 256, 256, 0, stream>>>(
      condW, y, ws + COND8_OFF);

  wavenet_pipe<<<256, 256, 0, stream>>>(samples, c, emb, WVp, WVx, Wo, Wob,
                                        Wol, Wobl, e1w, e1b, e2w, e2b, ws, out);
}